// Round 4
// baseline (281.379 us; speedup 1.0000x reference)
//
#include <hip/hip_runtime.h>

// P2B_XCorr: B=8, F=128, M=256, N=1024, H=64, O=128. fp32 I/O.
// R4: (1) k_main wave-private (no barriers in m-loop), grid x4 m-splits;
//     (2) k_cos via MFMA (bf16 staging, fp32 norms);
//     (3) k_a1 stages W1 in LDS (kills 64-line/wave uncoalesced reads).
// Frag layouts (HW-verified): A[m=lane&15][k=quad*8+j], B[k=quad*8+j][n=lane&15],
// D[row=quad*4+reg][col=lane&15].

#define BB 8
#define FF 128
#define MM 256
#define NN 1024
#define HH 64
#define OO 128
#define BN_EPS 1e-5f
#define COS_EPS 1e-8f

#define WS_U     0
#define WS_C2    64
#define WS_C3    128
#define WS_CC1   192
#define WS_W2F   256
#define WS_W3F   4352
#define WS_WC1F  8448
#define WS_A1    12544        // [b][m][h] fp32
#define WS_NT    143616
#define WS_NS    145664
#define WS_COSB  153856       // bf16 cos[b][m][n]
#define WS_P     1202432      // int-as-float p[b][n][64]

typedef __attribute__((ext_vector_type(8))) short short8;
typedef __attribute__((ext_vector_type(4))) float f32x4;

__device__ __forceinline__ unsigned short f2bf(float f){
  unsigned int u = __float_as_uint(f);
  return (unsigned short)((u + 0x7FFFu + ((u >> 16) & 1u)) >> 16);
}
__device__ __forceinline__ float bf2f(unsigned short u){
  return __uint_as_float(((unsigned int)u) << 16);
}
// round-half-up bf16 pack of two floats (3 VALU ops)
__device__ __forceinline__ unsigned int pack2rh(float a, float b){
  unsigned int ua = __float_as_uint(a) + 0x8000u;
  unsigned int ub = __float_as_uint(b) + 0x8000u;
  return (ua >> 16) | (ub & 0xFFFF0000u);
}
__device__ __forceinline__ unsigned short f2bfrh(float a){
  return (unsigned short)((__float_as_uint(a) + 0x8000u) >> 16);
}
__device__ __forceinline__ float dot4(float4 a, float4 b, float acc){
  acc = fmaf(a.x, b.x, acc); acc = fmaf(a.y, b.y, acc);
  acc = fmaf(a.z, b.z, acc); acc = fmaf(a.w, b.w, acc);
  return acc;
}

// ---------------- K0: fold BN params ----------------
__global__ __launch_bounds__(256) void k_fold(
    const float* W1, const float* W2, const float* W3, const float* Wc1,
    const float* g1, const float* b1, const float* m1, const float* v1,
    const float* g2, const float* b2, const float* m2, const float* v2,
    const float* g3, const float* b3, const float* m3, const float* v3,
    const float* gc1,const float* bc1,const float* mc1,const float* vc1,
    float* ws){
  int t = threadIdx.x;
  if (t < 64){
    float a1 = g1[t] / sqrtf(v1[t] + BN_EPS);
    ws[WS_U + t]   = a1 * W1[t*129];
    float a2 = g2[t] / sqrtf(v2[t] + BN_EPS);
    ws[WS_C2 + t]  = b2[t] - a2*m2[t];
    float a3 = g3[t] / sqrtf(v3[t] + BN_EPS);
    ws[WS_C3 + t]  = b3[t] - a3*m3[t];
    float ac = gc1[t] / sqrtf(vc1[t] + BN_EPS);
    ws[WS_CC1 + t] = bc1[t] - ac*mc1[t];
  }
  for (int i = t; i < 4096; i += 256){
    int g = i >> 6;
    float a2 = g2[g] / sqrtf(v2[g] + BN_EPS);
    ws[WS_W2F + i]  = a2 * W2[i];
    float a3 = g3[g] / sqrtf(v3[g] + BN_EPS);
    ws[WS_W3F + i]  = a3 * W3[i];
    float ac = gc1[g] / sqrtf(vc1[g] + BN_EPS);
    ws[WS_WC1F + i] = ac * Wc1[i];
  }
}

// ---------------- K1a: A1[b][m][h], W1 staged in LDS ----------------
__global__ __launch_bounds__(256) void k_a1(const float* t_, const float* W1,
    const float* g1, const float* b1, const float* m1, const float* v1, float* ws){
  __shared__ float W1s[64][133];   // stride 133 (5 mod 32) -> conflict-free h-major reads
  int t = threadIdx.x;
  int b = blockIdx.y;
  int m0 = blockIdx.x * 16;
  for (int idx = t; idx < 8192; idx += 256){
    int h = idx >> 7, f = idx & 127;
    W1s[h][f] = W1[h*129 + 1 + f];
  }
  __syncthreads();
  int h = t & 63, mg = t >> 6;
  const float* tp = t_ + (size_t)b*FF*MM + m0 + mg*4;
  float acc0=0.f, acc1=0.f, acc2=0.f, acc3=0.f;
  for (int f = 0; f < FF; f++){
    float wv = W1s[h][f];
    float4 tv = *(const float4*)&tp[(size_t)f*MM];
    acc0 = fmaf(wv, tv.x, acc0); acc1 = fmaf(wv, tv.y, acc1);
    acc2 = fmaf(wv, tv.z, acc2); acc3 = fmaf(wv, tv.w, acc3);
  }
  float a1 = g1[h] / sqrtf(v1[h] + BN_EPS);
  float c1 = b1[h] - a1*m1[h];
  float* dst = ws + WS_A1 + ((size_t)(b*MM + m0 + mg*4))*64 + h;
  dst[0]   = fmaf(a1, acc0, c1);
  dst[64]  = fmaf(a1, acc1, c1);
  dst[128] = fmaf(a1, acc2, c1);
  dst[192] = fmaf(a1, acc3, c1);
}

// ---------------- K1b: norms ----------------
__global__ __launch_bounds__(256) void k_norms(const float* t_, const float* s_, float* ws){
  int idx = blockIdx.x*256 + threadIdx.x;
  if (idx < BB*MM){
    int b = idx >> 8, m = idx & 255;
    float acc = 0.f;
    const float* tp = t_ + (size_t)b*FF*MM + m;
    for (int f = 0; f < FF; f++){ float x = tp[(size_t)f*MM]; acc = fmaf(x, x, acc); }
    ws[WS_NT + idx] = sqrtf(acc);
  } else if (idx < BB*MM + BB*NN){
    int j = idx - BB*MM;
    int b = j >> 10, n = j & 1023;
    float acc = 0.f;
    const float* sp = s_ + (size_t)b*FF*NN + n;
    for (int f = 0; f < FF; f++){ float x = sp[(size_t)f*NN]; acc = fmaf(x, x, acc); }
    ws[WS_NS + j] = sqrtf(acc);
  }
}

// ---------------- K2: cos via MFMA. tile 64m x 64n, 4 waves (one m-sub each) ----------------
__global__ __launch_bounds__(256) void k_cos(const float* t_, const float* s_, float* ws){
  __shared__ __align__(16) unsigned short tS[64][136];  // [m][f] bf16, 68-word stride
  __shared__ __align__(16) unsigned short sS[64][136];  // [n][f]
  __shared__ float ntS[64], nsS[64];
  int t = threadIdx.x;
  int lane = t & 63, w = t >> 6;
  int ln15 = lane & 15, quad = lane >> 4;
  int m0 = blockIdx.x*64, n0 = blockIdx.y*64, b = blockIdx.z;
  {
    int x = t & 63;
    const float* tb = t_ + (size_t)b*FF*MM + m0 + x;
    const float* sb = s_ + (size_t)b*FF*NN + n0 + x;
    #pragma unroll
    for (int k = 0; k < 16; k++){
      int fp = w*16 + k;   // f-pair 0..63
      float ta = tb[(size_t)(2*fp)*MM], tb2 = tb[(size_t)(2*fp+1)*MM];
      *(unsigned int*)&tS[x][2*fp] = pack2rh(ta, tb2);
      float sa = sb[(size_t)(2*fp)*NN], sb2 = sb[(size_t)(2*fp+1)*NN];
      *(unsigned int*)&sS[x][2*fp] = pack2rh(sa, sb2);
    }
    if (t < 64) ntS[t] = ws[WS_NT + b*MM + m0 + t];
    else if (t < 128) nsS[t-64] = ws[WS_NS + b*NN + n0 + (t-64)];
  }
  __syncthreads();
  short8 A4[4];
  #pragma unroll
  for (int kc = 0; kc < 4; kc++)
    A4[kc] = *(const short8*)&tS[w*16 + ln15][kc*32 + quad*8];
  float4 nt4 = *(const float4*)&ntS[w*16 + quad*4];
  unsigned short* cosw = (unsigned short*)(ws + WS_COSB);
  #pragma unroll
  for (int ns = 0; ns < 4; ns++){
    f32x4 acc = (f32x4){0.f,0.f,0.f,0.f};
    #pragma unroll
    for (int kc = 0; kc < 4; kc++){
      short8 B4 = *(const short8*)&sS[ns*16 + ln15][kc*32 + quad*8];
      acc = __builtin_amdgcn_mfma_f32_16x16x32_bf16(A4[kc], B4, acc, 0, 0, 0);
    }
    float nsv = nsS[ns*16 + ln15];
    int n = n0 + ns*16 + ln15;
    #pragma unroll
    for (int r = 0; r < 4; r++){
      int m = m0 + w*16 + quad*4 + r;
      float denom = fmaxf(nt4[r]*nsv, COS_EPS);
      float c = acc[r] * __builtin_amdgcn_rcpf(denom);
      cosw[(size_t)(b*MM + m)*NN + n] = f2bfrh(c);
    }
  }
}

// ---------------- K3: main MFMA m-loop, wave-private, no barriers ----------------
// grid (32, 8, 4), 256 thr = 4 independent waves. Wave w: m-pairs {ms*64+(mc*4+w)*2}.
__global__ __launch_bounds__(256) void k_main(const float* ws, int* Pi){
  __shared__ __align__(16) unsigned short h1S[4][64][72];  // per-wave [x][h] bf16
  __shared__ __align__(16) unsigned short h2W[4][16][72];  // per-wave scratch
  __shared__ float cosS[4][64];                            // per-wave cos slab
  int t = threadIdx.x;
  int lane = t & 63, w = t >> 6;
  int ln15 = lane & 15, quad = lane >> 4;
  int b = blockIdx.y;
  int n0 = blockIdx.x * 32;
  int ms = blockIdx.z;

  // weight A-frags + bias C-vectors (setup, RNE rounding)
  const float* w2p = ws + WS_W2F;
  const float* w3p = ws + WS_W3F;
  short8 W2A[4][2], W3A[4][2];
  f32x4 c2v[4], c3v[4];
  #pragma unroll
  for (int rt = 0; rt < 4; rt++){
    int g = rt*16 + ln15;
    #pragma unroll
    for (int kk = 0; kk < 2; kk++){
      short8 a2, a3;
      #pragma unroll
      for (int j = 0; j < 8; j++){
        int k = kk*32 + quad*8 + j;
        a2[j] = (short)f2bf(w2p[g*64 + k]);
        a3[j] = (short)f2bf(w3p[g*64 + k]);
      }
      W2A[rt][kk] = a2; W3A[rt][kk] = a3;
    }
    float4 cb2 = *(const float4*)&ws[WS_C2 + rt*16 + quad*4];
    float4 cb3 = *(const float4*)&ws[WS_C3 + rt*16 + quad*4];
    c2v[rt] = (f32x4){cb2.x, cb2.y, cb2.z, cb2.w};
    c3v[rt] = (f32x4){cb3.x, cb3.y, cb3.z, cb3.w};
  }
  int hq = ln15, xg = quad;     // build roles coincide with frag roles
  float4 u4 = *(const float4*)&ws[WS_U + hq*4];
  const float* A1b = ws + WS_A1 + (size_t)b*MM*64;
  const unsigned short* cosT = (const unsigned short*)(ws + WS_COSB);

  unsigned short* h1w = &h1S[w][0][0];
  unsigned short* h2w = &h2W[w][0][0];
  float* cw = &cosS[w][0];

  f32x4 p2[2][4];
  #pragma unroll
  for (int pa = 0; pa < 2; pa++)
    #pragma unroll
    for (int rt = 0; rt < 4; rt++) p2[pa][rt] = (f32x4){0.f,0.f,0.f,0.f};

  int mpL = lane >> 5, nlL = lane & 31;

  for (int mc = 0; mc < 8; mc++){
    int mbase = ms*64 + (mc*4 + w)*2;
    // per-wave staging: 1 u16 cos load, 2 float4 A1 loads
    float cv = bf2f(cosT[(size_t)(b*MM + mbase + mpL)*NN + n0 + nlL]);
    float4 a1lo = *(const float4*)&A1b[(size_t)(mbase    )*64 + hq*4];
    float4 a1hi = *(const float4*)&A1b[(size_t)(mbase + 1)*64 + hq*4];
    cw[mpL*32 + nlL] = cv;
    __asm__ volatile("s_waitcnt lgkmcnt(0)" ::: "memory");  // cos slab visible wave-wide
    // build h1: 16 iters, 4 h each, x = i*4+xg
    #pragma unroll
    for (int i = 0; i < 16; i++){
      int x = i*4 + xg;
      float c = cw[(i >= 8 ? 32 : 0) + (i & 7)*4 + xg];
      float4 a1 = (i >= 8) ? a1hi : a1lo;
      float v0 = fmaxf(fmaf(u4.x, c, a1.x), 0.f);
      float v1 = fmaxf(fmaf(u4.y, c, a1.y), 0.f);
      float v2 = fmaxf(fmaf(u4.z, c, a1.z), 0.f);
      float v3 = fmaxf(fmaf(u4.w, c, a1.w), 0.f);
      uint2 pr; pr.x = pack2rh(v0, v1); pr.y = pack2rh(v2, v3);
      *(uint2*)&h1w[x*72 + hq*4] = pr;
    }
    // 4 col-tiles: layer2 -> h2 scratch -> layer3 -> running max
    #pragma unroll
    for (int j = 0; j < 4; j++){
      const unsigned short* bp = &h1w[(j*16 + ln15)*72];
      short8 b0 = *(const short8*)&bp[quad*8];
      short8 b1 = *(const short8*)&bp[32 + quad*8];
      f32x4 acc[4];
      #pragma unroll
      for (int rt = 0; rt < 4; rt++){
        acc[rt] = __builtin_amdgcn_mfma_f32_16x16x32_bf16(W2A[rt][0], b0, c2v[rt], 0, 0, 0);
        acc[rt] = __builtin_amdgcn_mfma_f32_16x16x32_bf16(W2A[rt][1], b1, acc[rt], 0, 0, 0);
      }
      #pragma unroll
      for (int rt = 0; rt < 4; rt++){
        uint2 v;
        v.x = pack2rh(fmaxf(acc[rt][0], 0.f), fmaxf(acc[rt][1], 0.f));
        v.y = pack2rh(fmaxf(acc[rt][2], 0.f), fmaxf(acc[rt][3], 0.f));
        *(uint2*)&h2w[ln15*72 + rt*16 + quad*4] = v;
      }
      __asm__ volatile("s_waitcnt lgkmcnt(0)" ::: "memory");
      short8 e0 = *(const short8*)&h2w[ln15*72 + quad*8];
      short8 e1 = *(const short8*)&h2w[ln15*72 + 32 + quad*8];
      int par = j & 1;
      #pragma unroll
      for (int rt = 0; rt < 4; rt++){
        f32x4 a3 = __builtin_amdgcn_mfma_f32_16x16x32_bf16(W3A[rt][0], e0, c3v[rt], 0, 0, 0);
        a3 = __builtin_amdgcn_mfma_f32_16x16x32_bf16(W3A[rt][1], e1, a3, 0, 0, 0);
        #pragma unroll
        for (int r = 0; r < 4; r++) p2[par][rt][r] = fmaxf(p2[par][rt][r], a3[r]);
      }
    }
  }
  // combine via int-as-float atomicMax (values >= 0; poison 0xAA.. is negative)
  int* PbB = Pi + ((size_t)(b*NN + n0) << 6);
  #pragma unroll
  for (int pa = 0; pa < 2; pa++){
    int* Pn = PbB + ((pa*16 + ln15) << 6);
    #pragma unroll
    for (int rt = 0; rt < 4; rt++)
      #pragma unroll
      for (int r = 0; r < 4; r++)
        atomicMax(&Pn[rt*16 + quad*4 + r], __float_as_int(p2[pa][rt][r]));
  }
}

// ---------------- K4: tail (Wc1f/relu, Wc2+bias) fp32 ----------------
__global__ __launch_bounds__(256) void k_tail(const float* Wc2, const float* bc2,
                                              const float* ws, float* out){
  __shared__ float WT[64][68];
  __shared__ float pT[32][68];
  __shared__ float cS[32][68];
  int t = threadIdx.x;
  int n0 = blockIdx.x * 32;
  int b = blockIdx.y;
  for (int i = t; i < 4096; i += 256) WT[i >> 6][i & 63] = ws[WS_WC1F + i];
  const float* Pb = ws + WS_P + ((size_t)(b*NN + n0) << 6);
  for (int i = t; i < 2048; i += 256) pT[i >> 6][i & 63] = Pb[i];
  __syncthreads();
  {
    int n = t & 31, q = t >> 5;
    for (int k = 0; k < 8; k++){
      int g = q*8 + k;
      float acc = ws[WS_CC1 + g];
      for (int hs = 0; hs < 64; hs += 4){
        float4 wv = *(const float4*)&WT[g][hs];
        float4 pv = *(const float4*)&pT[n][hs];
        acc = dot4(wv, pv, acc);
      }
      cS[n][g] = fmaxf(acc, 0.f);
    }
  }
  __syncthreads();
  {
    int o = t & 127, hf = t >> 7;
    float bco = bc2[o];
    float accO[16];
    #pragma unroll
    for (int i = 0; i < 16; i++) accO[i] = bco;
    for (int hs = 0; hs < 64; hs += 4){
      float4 w4 = *(const float4*)&Wc2[o*64 + hs];
      #pragma unroll
      for (int i = 0; i < 16; i++){
        float4 cv = *(const float4*)&cS[hf*16 + i][hs];
        accO[i] = dot4(w4, cv, accO[i]);
      }
    }
    #pragma unroll
    for (int i = 0; i < 16; i++)
      out[((size_t)(b*OO + o))*NN + n0 + hf*16 + i] = accO[i];
  }
}

extern "C" void kernel_launch(void* const* d_in, const int* in_sizes, int n_in,
                              void* d_out, int out_size, void* d_ws, size_t ws_size,
                              hipStream_t stream){
  (void)in_sizes; (void)n_in; (void)out_size; (void)ws_size;
  const float* t_  = (const float*)d_in[0];
  const float* s_  = (const float*)d_in[1];
  const float* W1  = (const float*)d_in[2];
  const float* W2  = (const float*)d_in[3];
  const float* W3  = (const float*)d_in[4];
  const float* Wc1 = (const float*)d_in[5];
  const float* Wc2 = (const float*)d_in[6];
  const float* bc2 = (const float*)d_in[7];
  const float* g1 = (const float*)d_in[8],  *b1 = (const float*)d_in[9],
             * m1 = (const float*)d_in[10], *v1 = (const float*)d_in[11];
  const float* g2 = (const float*)d_in[12], *b2 = (const float*)d_in[13],
             * m2 = (const float*)d_in[14], *v2 = (const float*)d_in[15];
  const float* g3 = (const float*)d_in[16], *b3 = (const float*)d_in[17],
             * m3 = (const float*)d_in[18], *v3 = (const float*)d_in[19];
  const float* gc1 = (const float*)d_in[20], *bc1 = (const float*)d_in[21],
             * mc1 = (const float*)d_in[22], *vc1 = (const float*)d_in[23];
  float* ws = (float*)d_ws;
  float* out = (float*)d_out;

  k_fold<<<1, 256, 0, stream>>>(W1, W2, W3, Wc1,
      g1,b1,m1,v1, g2,b2,m2,v2, g3,b3,m3,v3, gc1,bc1,mc1,vc1, ws);
  k_a1<<<dim3(16, 8), 256, 0, stream>>>(t_, W1, g1, b1, m1, v1, ws);
  k_norms<<<40, 256, 0, stream>>>(t_, s_, ws);
  k_cos<<<dim3(4, 16, 8), 256, 0, stream>>>(t_, s_, ws);
  k_main<<<dim3(32, 8, 4), 256, 0, stream>>>(ws, (int*)(ws + WS_P));
  k_tail<<<dim3(32, 8), 256, 0, stream>>>(Wc2, bc2, ws, out);
}

// Round 6
// 228.398 us; speedup vs baseline: 1.2320x; 1.2320x over previous
//
#include <hip/hip_runtime.h>

// P2B_XCorr: B=8, F=128, M=256, N=1024, H=64, O=128. fp32 I/O.
// R6 = R5 with the cvt_pkrtz return-type fix (auto + bit_cast; __fp16x2 vs _Float16x2).
// R5 theory: (1) NO global atomics — per-block LDS cross-wave max reduce + plain store
//     of 2 m-split partials (R4: 2M atomicMax x 64B line-writes = 134 MB HBM = 147 us).
//     (2) f16 inside k_main/k_cos: v_cvt_pkrtz 1-op packs, v_pk_fma_f16 build,
//     mfma_f32_16x16x32_f16 (frag layout dtype-independent).
//     (3) k_norms 160 blocks, k_a1 256 blocks.
// Frag layouts (HW-verified): A[m=lane&15][k=quad*8+j], B[k=quad*8+j][n=lane&15],
// D[row=quad*4+reg][col=lane&15].

#define BB 8
#define FF 128
#define MM 256
#define NN 1024
#define HH 64
#define OO 128
#define BN_EPS 1e-5f
#define COS_EPS 1e-8f

// ws layout (float offsets); total 2,251,008 floats = 8.59 MiB
#define WS_U     0
#define WS_C2    64
#define WS_C3    128
#define WS_CC1   192
#define WS_W2F   256
#define WS_W3F   4352
#define WS_WC1F  8448
#define WS_A1    12544        // [b][m][h] fp32
#define WS_NT    143616       // [b][m] fp32  (NS follows contiguously)
#define WS_NS    145664       // [b][n] fp32
#define WS_COSH  153856       // f16 cos[b][m][n]  (1,048,576 floats)
#define WS_P     1202432      // fp32 partials [2][b][n][64]  (2 x 524288)
#define PS       524288

typedef _Float16 half2v __attribute__((ext_vector_type(2)));
typedef _Float16 half8  __attribute__((ext_vector_type(8)));
typedef __attribute__((ext_vector_type(4))) float f32x4;

__device__ __forceinline__ unsigned int pkh2(float a, float b){
  auto h = __builtin_amdgcn_cvt_pkrtz(a, b);   // v_cvt_pkrtz_f16_f32 (returns __fp16x2)
  return __builtin_bit_cast(unsigned int, h);
}
__device__ __forceinline__ half2v u2h(unsigned int u){
  return __builtin_bit_cast(half2v, u);
}
__device__ __forceinline__ unsigned int h2u(half2v v){
  return __builtin_bit_cast(unsigned int, v);
}
__device__ __forceinline__ float dot4(float4 a, float4 b, float acc){
  acc = fmaf(a.x, b.x, acc); acc = fmaf(a.y, b.y, acc);
  acc = fmaf(a.z, b.z, acc); acc = fmaf(a.w, b.w, acc);
  return acc;
}

// ---------------- K0: fold BN params ----------------
__global__ __launch_bounds__(256) void k_fold(
    const float* W1, const float* W2, const float* W3, const float* Wc1,
    const float* g1, const float* b1, const float* m1, const float* v1,
    const float* g2, const float* b2, const float* m2, const float* v2,
    const float* g3, const float* b3, const float* m3, const float* v3,
    const float* gc1,const float* bc1,const float* mc1,const float* vc1,
    float* ws){
  int t = threadIdx.x;
  if (t < 64){
    float a1 = g1[t] / sqrtf(v1[t] + BN_EPS);
    ws[WS_U + t]   = a1 * W1[t*129];
    float a2 = g2[t] / sqrtf(v2[t] + BN_EPS);
    ws[WS_C2 + t]  = b2[t] - a2*m2[t];
    float a3 = g3[t] / sqrtf(v3[t] + BN_EPS);
    ws[WS_C3 + t]  = b3[t] - a3*m3[t];
    float ac = gc1[t] / sqrtf(vc1[t] + BN_EPS);
    ws[WS_CC1 + t] = bc1[t] - ac*mc1[t];
  }
  for (int i = t; i < 4096; i += 256){
    int g = i >> 6;
    float a2 = g2[g] / sqrtf(v2[g] + BN_EPS);
    ws[WS_W2F + i]  = a2 * W2[i];
    float a3 = g3[g] / sqrtf(v3[g] + BN_EPS);
    ws[WS_W3F + i]  = a3 * W3[i];
    float ac = gc1[g] / sqrtf(vc1[g] + BN_EPS);
    ws[WS_WC1F + i] = ac * Wc1[i];
  }
}

// ---------------- K1a: A1[b][m][h], W1 staged in LDS, 256 blocks ----------------
__global__ __launch_bounds__(256) void k_a1(const float* t_, const float* W1,
    const float* g1, const float* b1, const float* m1, const float* v1, float* ws){
  __shared__ float W1s[64][133];   // stride 133 (5 mod 32): 64-lane h-reads = 2-way (free)
  int t = threadIdx.x;
  int b = blockIdx.y;
  int m0 = blockIdx.x * 8;
  for (int idx = t; idx < 8192; idx += 256){
    int h = idx >> 7, f = idx & 127;
    W1s[h][f] = W1[h*129 + 1 + f];
  }
  __syncthreads();
  int h = t & 63, mg = t >> 6;       // mg 0..3, each thread does 2 m
  const float* tp = t_ + (size_t)b*FF*MM + m0 + mg*2;
  float acc0 = 0.f, acc1 = 0.f;
  for (int f = 0; f < FF; f++){
    float wv = W1s[h][f];
    float2 tv = *(const float2*)&tp[(size_t)f*MM];
    acc0 = fmaf(wv, tv.x, acc0); acc1 = fmaf(wv, tv.y, acc1);
  }
  float a1 = g1[h] / sqrtf(v1[h] + BN_EPS);
  float c1 = b1[h] - a1*m1[h];
  float* dst = ws + WS_A1 + ((size_t)(b*MM + m0 + mg*2))*64 + h;
  dst[0]  = fmaf(a1, acc0, c1);
  dst[64] = fmaf(a1, acc1, c1);
}

// ---------------- K1b: norms, 160 blocks, 4-way f-split ----------------
__global__ __launch_bounds__(256) void k_norms(const float* t_, const float* s_, float* ws){
  __shared__ float red[4][64];
  int t = threadIdx.x;
  int x = t & 63, fq = t >> 6;
  int idx = blockIdx.x*64 + x;        // 0..10239 over [NT | NS]
  const float* ptr; size_t stride;
  if (idx < BB*MM){
    int b = idx >> 8, m = idx & 255;
    ptr = t_ + (size_t)b*FF*MM + m; stride = MM;
  } else {
    int j = idx - BB*MM;
    int b = j >> 10, n = j & 1023;
    ptr = s_ + (size_t)b*FF*NN + n; stride = NN;
  }
  float acc = 0.f;
  for (int f = fq*32; f < fq*32 + 32; f++){
    float v = ptr[(size_t)f*stride]; acc = fmaf(v, v, acc);
  }
  red[fq][x] = acc;
  __syncthreads();
  if (fq == 0)
    ws[WS_NT + idx] = sqrtf(red[0][x] + red[1][x] + red[2][x] + red[3][x]);
}

// ---------------- K2: cos via f16 MFMA. tile 64m x 64n ----------------
__global__ __launch_bounds__(256) void k_cos(const float* t_, const float* s_, float* ws){
  __shared__ __align__(16) unsigned short tS[64][136];  // [m][f] f16
  __shared__ __align__(16) unsigned short sS[64][136];  // [n][f] f16
  __shared__ float ntS[64], nsS[64];
  int t = threadIdx.x;
  int lane = t & 63, w = t >> 6;
  int ln15 = lane & 15, quad = lane >> 4;
  int m0 = blockIdx.x*64, n0 = blockIdx.y*64, b = blockIdx.z;
  {
    int x = t & 63;
    const float* tb = t_ + (size_t)b*FF*MM + m0 + x;
    const float* sb = s_ + (size_t)b*FF*NN + n0 + x;
    #pragma unroll
    for (int k = 0; k < 16; k++){
      int fp = w*16 + k;
      *(unsigned int*)&tS[x][2*fp] = pkh2(tb[(size_t)(2*fp)*MM], tb[(size_t)(2*fp+1)*MM]);
      *(unsigned int*)&sS[x][2*fp] = pkh2(sb[(size_t)(2*fp)*NN], sb[(size_t)(2*fp+1)*NN]);
    }
    if (t < 64) ntS[t] = ws[WS_NT + b*MM + m0 + t];
    else if (t < 128) nsS[t-64] = ws[WS_NS + b*NN + n0 + (t-64)];
  }
  __syncthreads();
  half8 A4[4];
  #pragma unroll
  for (int kc = 0; kc < 4; kc++)
    A4[kc] = *(const half8*)&tS[w*16 + ln15][kc*32 + quad*8];
  float4 nt4 = *(const float4*)&ntS[w*16 + quad*4];
  unsigned short* cosw = (unsigned short*)(ws + WS_COSH);
  #pragma unroll
  for (int ns = 0; ns < 4; ns++){
    f32x4 acc = (f32x4){0.f,0.f,0.f,0.f};
    #pragma unroll
    for (int kc = 0; kc < 4; kc++){
      half8 B4 = *(const half8*)&sS[ns*16 + ln15][kc*32 + quad*8];
      acc = __builtin_amdgcn_mfma_f32_16x16x32_f16(A4[kc], B4, acc, 0, 0, 0);
    }
    float nsv = nsS[ns*16 + ln15];
    int n = n0 + ns*16 + ln15;
    #pragma unroll
    for (int r = 0; r < 4; r++){
      int m = m0 + w*16 + quad*4 + r;
      float denom = fmaxf(nt4[r]*nsv, COS_EPS);
      float c = acc[r] * __builtin_amdgcn_rcpf(denom);
      cosw[(size_t)(b*MM + m)*NN + n] = (unsigned short)(pkh2(c, 0.f) & 0xFFFFu);
    }
  }
}

// ---------------- K3: main MFMA m-loop, wave-private, LDS cross-wave reduce ----------------
// grid (32, 8, 2), 256 thr = 4 waves. Wave w: m = ms*128 + (mc*4+w)*2, mc=0..15.
__global__ __launch_bounds__(256) void k_main(const float* ws, float* Pp){
  __shared__ __align__(16) unsigned short h1S[4][64][72];  // per-wave [x][h] f16 (36864 B)
  __shared__ __align__(16) unsigned short h2W[4][16][72];  // per-wave scratch (9216 B)
  __shared__ unsigned int cosD[4][64];                     // per-wave (c,c) dwords
  int t = threadIdx.x;
  int lane = t & 63, w = t >> 6;
  int ln15 = lane & 15, quad = lane >> 4;
  int b = blockIdx.y;
  int n0 = blockIdx.x * 32;
  int ms = blockIdx.z;

  // weight A-frags (f16) + bias C-vectors
  const float* w2p = ws + WS_W2F;
  const float* w3p = ws + WS_W3F;
  half8 W2A[4][2], W3A[4][2];
  f32x4 c2v[4], c3v[4];
  #pragma unroll
  for (int rt = 0; rt < 4; rt++){
    int g = rt*16 + ln15;
    #pragma unroll
    for (int kk = 0; kk < 2; kk++){
      half8 a2, a3;
      #pragma unroll
      for (int j = 0; j < 8; j++){
        int k = kk*32 + quad*8 + j;
        a2[j] = (_Float16)w2p[g*64 + k];
        a3[j] = (_Float16)w3p[g*64 + k];
      }
      W2A[rt][kk] = a2; W3A[rt][kk] = a3;
    }
    float4 cb2 = *(const float4*)&ws[WS_C2 + rt*16 + quad*4];
    float4 cb3 = *(const float4*)&ws[WS_C3 + rt*16 + quad*4];
    c2v[rt] = (f32x4){cb2.x, cb2.y, cb2.z, cb2.w};
    c3v[rt] = (f32x4){cb3.x, cb3.y, cb3.z, cb3.w};
  }
  int hq = ln15, xg = quad;
  float4 u4 = *(const float4*)&ws[WS_U + hq*4];
  half2v u01 = u2h(pkh2(u4.x, u4.y));
  half2v u23 = u2h(pkh2(u4.z, u4.w));
  const half2v zero = {(_Float16)0, (_Float16)0};
  const float* A1b = ws + WS_A1 + (size_t)b*MM*64;
  const unsigned short* cosT = (const unsigned short*)(ws + WS_COSH);

  unsigned short* h1w = &h1S[w][0][0];
  unsigned short* h2w = &h2W[w][0][0];
  unsigned int* cw = &cosD[w][0];

  f32x4 p2[2][4];
  #pragma unroll
  for (int pa = 0; pa < 2; pa++)
    #pragma unroll
    for (int rt = 0; rt < 4; rt++) p2[pa][rt] = (f32x4){0.f,0.f,0.f,0.f};

  int mpL = lane >> 5, nlL = lane & 31;

  for (int mc = 0; mc < 16; mc++){
    int mbase = ms*128 + (mc*4 + w)*2;
    // stage cos (duplicated-pair dword) + A1 as packed f16
    unsigned int cu = cosT[(size_t)(b*MM + mbase + mpL)*NN + n0 + nlL];
    float4 a1lo = *(const float4*)&A1b[(size_t)(mbase    )*64 + hq*4];
    float4 a1hi = *(const float4*)&A1b[(size_t)(mbase + 1)*64 + hq*4];
    cw[mpL*32 + nlL] = cu | (cu << 16);
    half2v al01 = u2h(pkh2(a1lo.x, a1lo.y)), al23 = u2h(pkh2(a1lo.z, a1lo.w));
    half2v ah01 = u2h(pkh2(a1hi.x, a1hi.y)), ah23 = u2h(pkh2(a1hi.z, a1hi.w));
    __asm__ volatile("s_waitcnt lgkmcnt(0)" ::: "memory");
    // build h1: 16 iters x 4 h (packed f16 fma+max)
    #pragma unroll
    for (int i = 0; i < 16; i++){
      int x = i*4 + xg;
      half2v c2 = u2h(cw[(i >= 8 ? 32 : 0) + (i & 7)*4 + xg]);
      half2v v01 = __builtin_elementwise_fma(u01, c2, (i >= 8) ? ah01 : al01);
      half2v v23 = __builtin_elementwise_fma(u23, c2, (i >= 8) ? ah23 : al23);
      v01 = __builtin_elementwise_max(v01, zero);
      v23 = __builtin_elementwise_max(v23, zero);
      uint2 pr; pr.x = h2u(v01); pr.y = h2u(v23);
      *(uint2*)&h1w[x*72 + hq*4] = pr;
    }
    // 4 col-tiles: layer2 -> h2 scratch -> layer3 -> running max
    #pragma unroll
    for (int j = 0; j < 4; j++){
      const unsigned short* bp = &h1w[(j*16 + ln15)*72];
      half8 b0 = *(const half8*)&bp[quad*8];
      half8 b1 = *(const half8*)&bp[32 + quad*8];
      f32x4 acc[4];
      #pragma unroll
      for (int rt = 0; rt < 4; rt++){
        acc[rt] = __builtin_amdgcn_mfma_f32_16x16x32_f16(W2A[rt][0], b0, c2v[rt], 0, 0, 0);
        acc[rt] = __builtin_amdgcn_mfma_f32_16x16x32_f16(W2A[rt][1], b1, acc[rt], 0, 0, 0);
      }
      #pragma unroll
      for (int rt = 0; rt < 4; rt++){
        uint2 v;
        v.x = pkh2(fmaxf(acc[rt][0], 0.f), fmaxf(acc[rt][1], 0.f));
        v.y = pkh2(fmaxf(acc[rt][2], 0.f), fmaxf(acc[rt][3], 0.f));
        *(uint2*)&h2w[ln15*72 + rt*16 + quad*4] = v;
      }
      __asm__ volatile("s_waitcnt lgkmcnt(0)" ::: "memory");
      half8 e0 = *(const half8*)&h2w[ln15*72 + quad*8];
      half8 e1 = *(const half8*)&h2w[ln15*72 + 32 + quad*8];
      int par = j & 1;
      #pragma unroll
      for (int rt = 0; rt < 4; rt++){
        f32x4 a3 = __builtin_amdgcn_mfma_f32_16x16x32_f16(W3A[rt][0], e0, c3v[rt], 0, 0, 0);
        a3 = __builtin_amdgcn_mfma_f32_16x16x32_f16(W3A[rt][1], e1, a3, 0, 0, 0);
        #pragma unroll
        for (int r = 0; r < 4; r++) p2[par][rt][r] = fmaxf(p2[par][rt][r], a3[r]);
      }
    }
  }
  // cross-wave LDS max reduce (reuse h1S as float[4][32][64]), then one coalesced store
  __syncthreads();
  float* red = (float*)&h1S[0][0][0];
  #pragma unroll
  for (int pa = 0; pa < 2; pa++)
    #pragma unroll
    for (int rt = 0; rt < 4; rt++){
      f32x4 v = p2[pa][rt];
      *(float4*)&red[(size_t)((w*32 + pa*16 + ln15)*64 + rt*16 + quad*4)] =
          make_float4(v[0], v[1], v[2], v[3]);
    }
  __syncthreads();
  float* dst = Pp + (size_t)ms*PS + ((size_t)(b*NN + n0) << 6);
  #pragma unroll
  for (int r2 = 0; r2 < 2; r2++){
    int o = t*8 + r2*4;
    float4 v0 = *(const float4*)&red[o];
    float4 v1 = *(const float4*)&red[2048 + o];
    float4 v2 = *(const float4*)&red[4096 + o];
    float4 v3 = *(const float4*)&red[6144 + o];
    float4 r4;
    r4.x = fmaxf(fmaxf(v0.x, v1.x), fmaxf(v2.x, v3.x));
    r4.y = fmaxf(fmaxf(v0.y, v1.y), fmaxf(v2.y, v3.y));
    r4.z = fmaxf(fmaxf(v0.z, v1.z), fmaxf(v2.z, v3.z));
    r4.w = fmaxf(fmaxf(v0.w, v1.w), fmaxf(v2.w, v3.w));
    *(float4*)&dst[o] = r4;
  }
}

// ---------------- K4: tail (max 2 partials, Wc1f/relu, Wc2+bias) fp32 ----------------
__global__ __launch_bounds__(256) void k_tail(const float* Wc2, const float* bc2,
                                              const float* ws, float* out){
  __shared__ float WT[64][68];
  __shared__ float pT[32][68];
  __shared__ float cS[32][68];
  int t = threadIdx.x;
  int n0 = blockIdx.x * 32;
  int b = blockIdx.y;
  for (int i = t; i < 4096; i += 256) WT[i >> 6][i & 63] = ws[WS_WC1F + i];
  const float* P0 = ws + WS_P + ((size_t)(b*NN + n0) << 6);
  const float* P1 = P0 + PS;
  for (int i = t; i < 2048; i += 256) pT[i >> 6][i & 63] = fmaxf(P0[i], P1[i]);
  __syncthreads();
  {
    int n = t & 31, q = t >> 5;
    for (int k = 0; k < 8; k++){
      int g = q*8 + k;
      float acc = ws[WS_CC1 + g];
      for (int hs = 0; hs < 64; hs += 4){
        float4 wv = *(const float4*)&WT[g][hs];
        float4 pv = *(const float4*)&pT[n][hs];
        acc = dot4(wv, pv, acc);
      }
      cS[n][g] = fmaxf(acc, 0.f);
    }
  }
  __syncthreads();
  {
    int o = t & 127, hf = t >> 7;
    float bco = bc2[o];
    float accO[16];
    #pragma unroll
    for (int i = 0; i < 16; i++) accO[i] = bco;
    for (int hs = 0; hs < 64; hs += 4){
      float4 w4 = *(const float4*)&Wc2[o*64 + hs];
      #pragma unroll
      for (int i = 0; i < 16; i++){
        float4 cv = *(const float4*)&cS[hf*16 + i][hs];
        accO[i] = dot4(w4, cv, accO[i]);
      }
    }
    #pragma unroll
    for (int i = 0; i < 16; i++)
      out[((size_t)(b*OO + o))*NN + n0 + hf*16 + i] = accO[i];
  }
}

extern "C" void kernel_launch(void* const* d_in, const int* in_sizes, int n_in,
                              void* d_out, int out_size, void* d_ws, size_t ws_size,
                              hipStream_t stream){
  (void)in_sizes; (void)n_in; (void)out_size; (void)ws_size;
  const float* t_  = (const float*)d_in[0];
  const float* s_  = (const float*)d_in[1];
  const float* W1  = (const float*)d_in[2];
  const float* W2  = (const float*)d_in[3];
  const float* W3  = (const float*)d_in[4];
  const float* Wc1 = (const float*)d_in[5];
  const float* Wc2 = (const float*)d_in[6];
  const float* bc2 = (const float*)d_in[7];
  const float* g1 = (const float*)d_in[8],  *b1 = (const float*)d_in[9],
             * m1 = (const float*)d_in[10], *v1 = (const float*)d_in[11];
  const float* g2 = (const float*)d_in[12], *b2 = (const float*)d_in[13],
             * m2 = (const float*)d_in[14], *v2 = (const float*)d_in[15];
  const float* g3 = (const float*)d_in[16], *b3 = (const float*)d_in[17],
             * m3 = (const float*)d_in[18], *v3 = (const float*)d_in[19];
  const float* gc1 = (const float*)d_in[20], *bc1 = (const float*)d_in[21],
             * mc1 = (const float*)d_in[22], *vc1 = (const float*)d_in[23];
  float* ws = (float*)d_ws;
  float* out = (float*)d_out;

  k_fold<<<1, 256, 0, stream>>>(W1, W2, W3, Wc1,
      g1,b1,m1,v1, g2,b2,m2,v2, g3,b3,m3,v3, gc1,bc1,mc1,vc1, ws);
  k_a1<<<dim3(32, 8), 256, 0, stream>>>(t_, W1, g1, b1, m1, v1, ws);
  k_norms<<<160, 256, 0, stream>>>(t_, s_, ws);
  k_cos<<<dim3(4, 16, 8), 256, 0, stream>>>(t_, s_, ws);
  k_main<<<dim3(32, 8, 2), 256, 0, stream>>>(ws, ws + WS_P);
  k_tail<<<dim3(32, 8), 256, 0, stream>>>(Wc2, bc2, ws, out);
}

// Round 8
// 188.003 us; speedup vs baseline: 1.4967x; 1.2149x over previous
//
#include <hip/hip_runtime.h>

// P2B_XCorr: B=8, F=128, M=256, N=1024, H=64, O=128. fp32 I/O.
// R8 = R7 + cross-parity max combine (R7 bug: waves 0/2 and 1/3 share (n,g)
//   territory over disjoint m-parities; both plain-stored to the same P addrs —
//   a silent overwrite race losing half the max). Waves 2,3 park partials in the
//   retired h2W scratch; waves 0,1 merge + store.
// k_main: wave w owns x=16 n-columns for one m-parity; h1 B-frags built directly
//   in registers (build layout == B-operand layout); only h2 transpose uses LDS
//   (per-wave, 1 wait/mc); p in VGPRs. A1 prepacked f16. 4 launches.
// Frag layouts (HW-verified): A[m=lane&15][k=quad*8+j], B[k=quad*8+j][n=lane&15],
// D[row=quad*4+reg][col=lane&15].

#define BB 8
#define FF 128
#define MM 256
#define NN 1024
#define HH 64
#define OO 128
#define BN_EPS 1e-5f
#define COS_EPS 1e-8f

// ws layout (float offsets); total 2,251,008 floats = 8.59 MiB (proven envelope)
#define WS_U     0
#define WS_C2    64
#define WS_C3    128
#define WS_CC1   192
#define WS_W2F   256
#define WS_W3F   4352
#define WS_WC1F  8448
#define WS_A1    12544        // f16 A1H[b][m][64]
#define WS_NT    143616       // [b][m] fp32 (NS contiguous after)
#define WS_NS    145664       // [b][n] fp32
#define WS_COSH  153856       // f16 cos[b][m][n]
#define WS_P     1202432      // fp32 partials [2][b][n][64]
#define PS       524288

typedef _Float16 half2v __attribute__((ext_vector_type(2)));
typedef _Float16 half8  __attribute__((ext_vector_type(8)));
typedef __attribute__((ext_vector_type(4))) float f32x4;

__device__ __forceinline__ unsigned int pkh2(float a, float b){
  auto h = __builtin_amdgcn_cvt_pkrtz(a, b);
  return __builtin_bit_cast(unsigned int, h);
}
__device__ __forceinline__ half2v u2h(unsigned int u){
  return __builtin_bit_cast(half2v, u);
}
__device__ __forceinline__ unsigned int h2u(half2v v){
  return __builtin_bit_cast(unsigned int, v);
}
__device__ __forceinline__ unsigned int relu2(unsigned int d){
  half2v v = __builtin_elementwise_max(u2h(d), (half2v){(_Float16)0, (_Float16)0});
  return h2u(v);
}
__device__ __forceinline__ unsigned int bh1(unsigned int up, half2v c, unsigned int ap){
  half2v v = __builtin_elementwise_fma(u2h(up), c, u2h(ap));
  v = __builtin_elementwise_max(v, (half2v){(_Float16)0, (_Float16)0});
  return h2u(v);
}
__device__ __forceinline__ float dot4(float4 a, float4 b, float acc){
  acc = fmaf(a.x, b.x, acc); acc = fmaf(a.y, b.y, acc);
  acc = fmaf(a.z, b.z, acc); acc = fmaf(a.w, b.w, acc);
  return acc;
}

// ---------------- K1: prep (role-split: a1 | norms | fold) ----------------
__global__ __launch_bounds__(256) void k_prep(const float* t_, const float* s_,
    const float* W1, const float* W2, const float* W3, const float* Wc1,
    const float* g1, const float* b1, const float* m1, const float* v1,
    const float* g2, const float* b2, const float* m2, const float* v2,
    const float* g3, const float* b3, const float* m3, const float* v3,
    const float* gc1,const float* bc1,const float* mc1,const float* vc1,
    float* ws){
  __shared__ float W1s[64][133];
  int t = threadIdx.x;
  int bx = blockIdx.x;
  if (bx < 256){
    // ---- A1H[b][m][h] (f16) ----
    int b = bx >> 5, m0 = (bx & 31)*8;
    for (int idx = t; idx < 8192; idx += 256){
      int h = idx >> 7, f = idx & 127;
      W1s[h][f] = W1[h*129 + 1 + f];
    }
    __syncthreads();
    int h = t & 63, mg = t >> 6;
    const float* tp = t_ + (size_t)b*FF*MM + m0 + mg*2;
    float acc0 = 0.f, acc1 = 0.f;
    for (int f = 0; f < FF; f++){
      float wv = W1s[h][f];
      float2 tv = *(const float2*)&tp[(size_t)f*MM];
      acc0 = fmaf(wv, tv.x, acc0); acc1 = fmaf(wv, tv.y, acc1);
    }
    float a1 = g1[h] / sqrtf(v1[h] + BN_EPS);
    float c1 = b1[h] - a1*m1[h];
    unsigned short* dst = (unsigned short*)(ws + WS_A1) + ((size_t)(b*MM + m0 + mg*2))*64 + h;
    dst[0]  = (unsigned short)(pkh2(fmaf(a1, acc0, c1), 0.f) & 0xFFFFu);
    dst[64] = (unsigned short)(pkh2(fmaf(a1, acc1, c1), 0.f) & 0xFFFFu);
  } else if (bx < 416){
    // ---- norms ----
    __shared__ float red[4][64];
    int x = t & 63, fq = t >> 6;
    int idx = (bx - 256)*64 + x;
    const float* ptr; size_t stride;
    if (idx < BB*MM){
      int b = idx >> 8, m = idx & 255;
      ptr = t_ + (size_t)b*FF*MM + m; stride = MM;
    } else {
      int j = idx - BB*MM;
      int b = j >> 10, n = j & 1023;
      ptr = s_ + (size_t)b*FF*NN + n; stride = NN;
    }
    float acc = 0.f;
    for (int f = fq*32; f < fq*32 + 32; f++){
      float v = ptr[(size_t)f*stride]; acc = fmaf(v, v, acc);
    }
    red[fq][x] = acc;
    __syncthreads();
    if (fq == 0)
      ws[WS_NT + idx] = sqrtf(red[0][x] + red[1][x] + red[2][x] + red[3][x]);
  } else {
    // ---- fold ----
    if (t < 64){
      float a1 = g1[t] / sqrtf(v1[t] + BN_EPS);
      ws[WS_U + t]   = a1 * W1[t*129];
      float a2 = g2[t] / sqrtf(v2[t] + BN_EPS);
      ws[WS_C2 + t]  = b2[t] - a2*m2[t];
      float a3 = g3[t] / sqrtf(v3[t] + BN_EPS);
      ws[WS_C3 + t]  = b3[t] - a3*m3[t];
      float ac = gc1[t] / sqrtf(vc1[t] + BN_EPS);
      ws[WS_CC1 + t] = bc1[t] - ac*mc1[t];
    }
    for (int i = t; i < 4096; i += 256){
      int g = i >> 6;
      float a2 = g2[g] / sqrtf(v2[g] + BN_EPS);
      ws[WS_W2F + i]  = a2 * W2[i];
      float a3 = g3[g] / sqrtf(v3[g] + BN_EPS);
      ws[WS_W3F + i]  = a3 * W3[i];
      float ac = gc1[g] / sqrtf(vc1[g] + BN_EPS);
      ws[WS_WC1F + i] = ac * Wc1[i];
    }
  }
}

// ---------------- K2: cos via f16 MFMA. tile 64m x 64n ----------------
__global__ __launch_bounds__(256) void k_cos(const float* t_, const float* s_, float* ws){
  __shared__ __align__(16) unsigned short tS[64][136];
  __shared__ __align__(16) unsigned short sS[64][136];
  __shared__ float ntS[64], nsS[64];
  int t = threadIdx.x;
  int lane = t & 63, w = t >> 6;
  int ln15 = lane & 15, quad = lane >> 4;
  int m0 = blockIdx.x*64, n0 = blockIdx.y*64, b = blockIdx.z;
  {
    int x = t & 63;
    const float* tb = t_ + (size_t)b*FF*MM + m0 + x;
    const float* sb = s_ + (size_t)b*FF*NN + n0 + x;
    #pragma unroll
    for (int k = 0; k < 16; k++){
      int fp = w*16 + k;
      *(unsigned int*)&tS[x][2*fp] = pkh2(tb[(size_t)(2*fp)*MM], tb[(size_t)(2*fp+1)*MM]);
      *(unsigned int*)&sS[x][2*fp] = pkh2(sb[(size_t)(2*fp)*NN], sb[(size_t)(2*fp+1)*NN]);
    }
    if (t < 64) ntS[t] = ws[WS_NT + b*MM + m0 + t];
    else if (t < 128) nsS[t-64] = ws[WS_NS + b*NN + n0 + (t-64)];
  }
  __syncthreads();
  half8 A4[4];
  #pragma unroll
  for (int kc = 0; kc < 4; kc++)
    A4[kc] = *(const half8*)&tS[w*16 + ln15][kc*32 + quad*8];
  float4 nt4 = *(const float4*)&ntS[w*16 + quad*4];
  unsigned short* cosw = (unsigned short*)(ws + WS_COSH);
  #pragma unroll
  for (int ns = 0; ns < 4; ns++){
    f32x4 acc = (f32x4){0.f,0.f,0.f,0.f};
    #pragma unroll
    for (int kc = 0; kc < 4; kc++){
      half8 B4 = *(const half8*)&sS[ns*16 + ln15][kc*32 + quad*8];
      acc = __builtin_amdgcn_mfma_f32_16x16x32_f16(A4[kc], B4, acc, 0, 0, 0);
    }
    float nsv = nsS[ns*16 + ln15];
    int n = n0 + ns*16 + ln15;
    #pragma unroll
    for (int r = 0; r < 4; r++){
      int m = m0 + w*16 + quad*4 + r;
      float denom = fmaxf(nt4[r]*nsv, COS_EPS);
      float c = acc[r] * __builtin_amdgcn_rcpf(denom);
      cosw[(size_t)(b*MM + m)*NN + n] = (unsigned short)(pkh2(c, 0.f) & 0xFFFFu);
    }
  }
}

// ---------------- K3: main. grid (32,8,2), 4 waves; wave w: m-parity w>>1, n-half w&1 ----------------
__global__ __launch_bounds__(256, 3) void k_main(const float* ws, float* Pp){
  __shared__ __align__(16) unsigned short h2W[4][16][72];  // per-wave [x16][g64+pad]
  int t = threadIdx.x;
  int lane = t & 63, w = t >> 6;
  int ln15 = lane & 15, quad = lane >> 4;
  int b = blockIdx.y;
  int n0 = blockIdx.x * 32;
  int ms = blockIdx.z;

  // weight A-frags (f16) + bias C-vectors
  const float* w2p = ws + WS_W2F;
  const float* w3p = ws + WS_W3F;
  half8 W2A[4][2], W3A[4][2];
  f32x4 c2v[4], c3v[4];
  #pragma unroll
  for (int rt = 0; rt < 4; rt++){
    int g = rt*16 + ln15;
    #pragma unroll
    for (int kk = 0; kk < 2; kk++){
      half8 a2, a3;
      #pragma unroll
      for (int j = 0; j < 8; j++){
        int k = kk*32 + quad*8 + j;
        a2[j] = (_Float16)w2p[g*64 + k];
        a3[j] = (_Float16)w3p[g*64 + k];
      }
      W2A[rt][kk] = a2; W3A[rt][kk] = a3;
    }
    float4 cb2 = *(const float4*)&ws[WS_C2 + rt*16 + quad*4];
    float4 cb3 = *(const float4*)&ws[WS_C3 + rt*16 + quad*4];
    c2v[rt] = (f32x4){cb2.x, cb2.y, cb2.z, cb2.w};
    c3v[rt] = (f32x4){cb3.x, cb3.y, cb3.z, cb3.w};
  }
  // u[h] packed pairs for this lane's h-chunks
  unsigned int upk[2][4];
  #pragma unroll
  for (int kk = 0; kk < 2; kk++){
    float4 ua = *(const float4*)&ws[WS_U + kk*32 + quad*8];
    float4 ub = *(const float4*)&ws[WS_U + kk*32 + quad*8 + 4];
    upk[kk][0] = pkh2(ua.x, ua.y); upk[kk][1] = pkh2(ua.z, ua.w);
    upk[kk][2] = pkh2(ub.x, ub.y); upk[kk][3] = pkh2(ub.z, ub.w);
  }
  const unsigned short* A1H = (const unsigned short*)(ws + WS_A1) + (size_t)b*MM*64;
  int mp = w >> 1;                                  // m-parity handled by this wave
  int n  = n0 + (w & 1)*16 + ln15;                  // this lane's x/n
  const unsigned short* cosP = (const unsigned short*)(ws + WS_COSH)
                               + (size_t)b*MM*NN + n;
  unsigned short* h2w = &h2W[w][0][0];

  f32x4 p[4];
  #pragma unroll
  for (int rt = 0; rt < 4; rt++) p[rt] = (f32x4){0.f,0.f,0.f,0.f};

  int m0i = ms*128 + mp;
  unsigned int cu = cosP[(size_t)m0i*NN];
  uint4 a1a = *(const uint4*)&A1H[(size_t)m0i*64 + quad*8];
  uint4 a1b = *(const uint4*)&A1H[(size_t)m0i*64 + 32 + quad*8];

  for (int mc = 0; mc < 64; mc++){
    // prefetch next mc
    int mN = ms*128 + (mc < 63 ? (mc + 1) : 63)*2 + mp;
    unsigned int cuN = cosP[(size_t)mN*NN];
    uint4 a1aN = *(const uint4*)&A1H[(size_t)mN*64 + quad*8];
    uint4 a1bN = *(const uint4*)&A1H[(size_t)mN*64 + 32 + quad*8];

    unsigned int cd = cu | (cu << 16);
    half2v ch = u2h(cd);
    uint4 q0, q1;
    q0.x = bh1(upk[0][0], ch, a1a.x); q0.y = bh1(upk[0][1], ch, a1a.y);
    q0.z = bh1(upk[0][2], ch, a1a.z); q0.w = bh1(upk[0][3], ch, a1a.w);
    q1.x = bh1(upk[1][0], ch, a1b.x); q1.y = bh1(upk[1][1], ch, a1b.y);
    q1.z = bh1(upk[1][2], ch, a1b.z); q1.w = bh1(upk[1][3], ch, a1b.w);
    half8 b0h = __builtin_bit_cast(half8, q0);
    half8 b1h = __builtin_bit_cast(half8, q1);

    // layer 2
    f32x4 acc[4];
    #pragma unroll
    for (int rt = 0; rt < 4; rt++){
      acc[rt] = __builtin_amdgcn_mfma_f32_16x16x32_f16(W2A[rt][0], b0h, c2v[rt], 0, 0, 0);
      acc[rt] = __builtin_amdgcn_mfma_f32_16x16x32_f16(W2A[rt][1], b1h, acc[rt], 0, 0, 0);
    }
    // relu + pack + h2 transpose write (g = rt*16 + quad*4 + r, row x = ln15)
    #pragma unroll
    for (int rt = 0; rt < 4; rt++){
      uint2 vv;
      vv.x = relu2(pkh2(acc[rt][0], acc[rt][1]));
      vv.y = relu2(pkh2(acc[rt][2], acc[rt][3]));
      *(uint2*)&h2w[ln15*72 + rt*16 + quad*4] = vv;
    }
    __asm__ volatile("s_waitcnt lgkmcnt(0)" ::: "memory");
    half8 e0 = *(const half8*)&h2w[ln15*72 + quad*8];
    half8 e1 = *(const half8*)&h2w[ln15*72 + 32 + quad*8];
    // layer 3 + running max
    #pragma unroll
    for (int rt = 0; rt < 4; rt++){
      f32x4 a3 = __builtin_amdgcn_mfma_f32_16x16x32_f16(W3A[rt][0], e0, c3v[rt], 0, 0, 0);
      a3 = __builtin_amdgcn_mfma_f32_16x16x32_f16(W3A[rt][1], e1, a3, 0, 0, 0);
      #pragma unroll
      for (int r = 0; r < 4; r++) p[rt][r] = fmaxf(p[rt][r], a3[r]);
    }
    cu = cuN; a1a = a1aN; a1b = a1bN;
  }

  // cross-parity combine (R7 bug fix): waves 2,3 (odd-m) park partials in the
  // retired h2W scratch (stride-66 float striping); waves 0,1 merge + store.
  __syncthreads();
  float* redBuf = (float*)&h2W[0][0][0];   // 2304 floats available; use 32x66=2112
  if (w >= 2){
    #pragma unroll
    for (int rt = 0; rt < 4; rt++){
      f32x4 v = p[rt];
      *(float4*)&redBuf[(size_t)(((w & 1)*16 + ln15)*66 + rt*16 + quad*4)] =
          make_float4(v[0], v[1], v[2], v[3]);
    }
  }
  __syncthreads();
  if (w < 2){
    float* Pb = Pp + (size_t)ms*PS + ((size_t)(b*NN + n) << 6);
    #pragma unroll
    for (int rt = 0; rt < 4; rt++){
      float4 o = *(const float4*)&redBuf[(size_t)(((w & 1)*16 + ln15)*66 + rt*16 + quad*4)];
      float4 r4;
      r4.x = fmaxf(p[rt][0], o.x);
      r4.y = fmaxf(p[rt][1], o.y);
      r4.z = fmaxf(p[rt][2], o.z);
      r4.w = fmaxf(p[rt][3], o.w);
      *(float4*)&Pb[rt*16 + quad*4] = r4;
    }
  }
}

// ---------------- K4: tail (max 2 partials, Wc1f/relu, Wc2+bias) fp32 ----------------
__global__ __launch_bounds__(256) void k_tail(const float* Wc2, const float* bc2,
                                              const float* ws, float* out){
  __shared__ float WT[64][68];
  __shared__ float pT[32][68];
  __shared__ float cS[32][68];
  int t = threadIdx.x;
  int n0 = blockIdx.x * 32;
  int b = blockIdx.y;
  for (int i = t; i < 4096; i += 256) WT[i >> 6][i & 63] = ws[WS_WC1F + i];
  const float* P0 = ws + WS_P + ((size_t)(b*NN + n0) << 6);
  const float* P1 = P0 + PS;
  for (int i = t; i < 2048; i += 256) pT[i >> 6][i & 63] = fmaxf(P0[i], P1[i]);
  __syncthreads();
  {
    int n = t & 31, q = t >> 5;
    for (int k = 0; k < 8; k++){
      int g = q*8 + k;
      float acc = ws[WS_CC1 + g];
      for (int hs = 0; hs < 64; hs += 4){
        float4 wv = *(const float4*)&WT[g][hs];
        float4 pv = *(const float4*)&pT[n][hs];
        acc = dot4(wv, pv, acc);
      }
      cS[n][g] = fmaxf(acc, 0.f);
    }
  }
  __syncthreads();
  {
    int o = t & 127, hf = t >> 7;
    float bco = bc2[o];
    float accO[16];
    #pragma unroll
    for (int i = 0; i < 16; i++) accO[i] = bco;
    for (int hs = 0; hs < 64; hs += 4){
      float4 w4 = *(const float4*)&Wc2[o*64 + hs];
      #pragma unroll
      for (int i = 0; i < 16; i++){
        float4 cv = *(const float4*)&cS[hf*16 + i][hs];
        accO[i] = dot4(w4, cv, accO[i]);
      }
    }
    #pragma unroll
    for (int i = 0; i < 16; i++)
      out[((size_t)(b*OO + o))*NN + n0 + hf*16 + i] = accO[i];
  }
}

extern "C" void kernel_launch(void* const* d_in, const int* in_sizes, int n_in,
                              void* d_out, int out_size, void* d_ws, size_t ws_size,
                              hipStream_t stream){
  (void)in_sizes; (void)n_in; (void)out_size; (void)ws_size;
  const float* t_  = (const float*)d_in[0];
  const float* s_  = (const float*)d_in[1];
  const float* W1  = (const float*)d_in[2];
  const float* W2  = (const float*)d_in[3];
  const float* W3  = (const float*)d_in[4];
  const float* Wc1 = (const float*)d_in[5];
  const float* Wc2 = (const float*)d_in[6];
  const float* bc2 = (const float*)d_in[7];
  const float* g1 = (const float*)d_in[8],  *b1 = (const float*)d_in[9],
             * m1 = (const float*)d_in[10], *v1 = (const float*)d_in[11];
  const float* g2 = (const float*)d_in[12], *b2 = (const float*)d_in[13],
             * m2 = (const float*)d_in[14], *v2 = (const float*)d_in[15];
  const float* g3 = (const float*)d_in[16], *b3 = (const float*)d_in[17],
             * m3 = (const float*)d_in[18], *v3 = (const float*)d_in[19];
  const float* gc1 = (const float*)d_in[20], *bc1 = (const float*)d_in[21],
             * mc1 = (const float*)d_in[22], *vc1 = (const float*)d_in[23];
  float* ws = (float*)d_ws;
  float* out = (float*)d_out;

  k_prep<<<417, 256, 0, stream>>>(t_, s_, W1, W2, W3, Wc1,
      g1,b1,m1,v1, g2,b2,m2,v2, g3,b3,m3,v3, gc1,bc1,mc1,vc1, ws);
  k_cos<<<dim3(4, 16, 8), 256, 0, stream>>>(t_, s_, ws);
  k_main<<<dim3(32, 8, 2), 256, 0, stream>>>(ws, ws + WS_P);
  k_tail<<<dim3(32, 8), 256, 0, stream>>>(Wc2, bc2, ws, out);
}